// Round 5
// baseline (174.669 us; speedup 1.0000x reference)
//
#include <hip/hip_runtime.h>
#include <math.h>

#define BATCH 64
#define HH 512
#define WW 512
#define KRAD 15
#define KSZ 31
#define NTOT ((size_t)BATCH * HH * WW)
#define TILE_Y 32
#define NCHUNK (HH / TILE_Y)            // 16
#define NBLK (BATCH * NCHUNK)           // 1024 blocks
#define CH 8                            // rows per batch
#define NCH (TILE_Y / CH)               // 4

// ---------------------------------------------------------------------------
// V-first separable box + fused loss. Block = 512 threads (8 waves), one
// thread per column x. Per 8-row batch:
//   1) vertical running 31-sum from global targ (register),
//   2) 512-wide horizontal prefix: wave shuffle-scan + cross-wave fixup
//      (wtot LDS) -> Pbuf LDS row (fp32),
//   3) windowed diff P[x+15]-P[x-16], loss math, accumulate.
// LDS = 16.3 KB -> 4 blocks/CU (32 waves, 100% occupancy ceiling).
// ---------------------------------------------------------------------------
__global__ __launch_bounds__(512, 8) void mega_kernel(const float* __restrict__ logits,
                                                      const float* __restrict__ targ,
                                                      float* __restrict__ pbuf) {
    __shared__ float Pbuf[CH][WW];      // 16 KB
    __shared__ float wtot[CH][8];       // 256 B

    const int b     = blockIdx.x >> 4;          // batch index
    const int chunk = blockIdx.x & (NCHUNK - 1);
    const int y0    = chunk * TILE_Y;

    const int x    = threadIdx.x;               // column 0..511
    const int wave = x >> 6;
    const int lane = x & 63;

    const float* tcol = targ   + (size_t)b * HH * WW + x;
    const float* Lcol = logits + (size_t)b * HH * WW + x;

    // vertical warmup: rows [y0-15, y0+15] clipped low (high side < 512)
    float vsum = 0.0f;
    {
        int lo = y0 - KRAD; if (lo < 0) lo = 0;
        for (int k = lo; k <= y0 + KRAD; ++k) vsum += tcol[k * WW];
    }

    const float inv_ksq = 1.0f / (float)(KSZ * KSZ);
    float a_wbce = 0.0f, a_int = 0.0f, a_tot = 0.0f;

    for (int c = 0; c < NCH; ++c) {
        const int yb = y0 + c * CH;

        // ---- vertical running sums + wave-local scans for 8 rows ----
        float incl[CH];
#pragma unroll
        for (int j = 0; j < CH; ++j) {
            const int yy = yb + j;
            float V = vsum;                     // vertical 31-sum at row yy
            // slide window for next row
            const int add = yy + KRAD + 1;
            const int sub = yy - KRAD;
            if (add < HH)  vsum += tcol[(size_t)add * WW];
            if (sub >= 0)  vsum -= tcol[(size_t)sub * WW];
            // wave-inclusive scan of V across 64 lanes
            float s = V;
#pragma unroll
            for (int d = 1; d < 64; d <<= 1) {
                float n = __shfl_up(s, d, 64);
                if (lane >= d) s += n;
            }
            incl[j] = s;
            if (lane == 63) wtot[j][wave] = s;  // wave total
        }
        __syncthreads();

        // ---- cross-wave fixup -> full 512-wide prefix rows in LDS ----
#pragma unroll
        for (int j = 0; j < CH; ++j) {
            float off = 0.0f;
            for (int w = 0; w < wave; ++w) off += wtot[j][w];   // broadcast reads
            Pbuf[j][x] = incl[j] + off;
        }
        __syncthreads();

        // ---- windowed diff + loss math ----
        const int xh = (x + KRAD > WW - 1) ? (WW - 1) : (x + KRAD);
#pragma unroll
        for (int j = 0; j < CH; ++j) {
            const int yy = yb + j;
            const float hi = Pbuf[j][xh];
            const float lo = (x >= KRAD + 1) ? Pbuf[j][x - KRAD - 1] : 0.0f;
            const float s  = (hi - lo) * inv_ksq;

            const float t = tcol[(size_t)yy * WW];
            const float L = __builtin_nontemporal_load(Lcol + (size_t)yy * WW);

            const float weit = 1.0f + 5.0f * fabsf(s - t);
            const float e  = __expf(-fabsf(L));
            const float r  = __builtin_amdgcn_rcpf(1.0f + e);
            const float lg = __logf(1.0f + e);          // softplus(-|L|)
            const float sp  = fmaxf(L, 0.0f) + lg;      // softplus(L)
            const float bce = sp - t * L;
            const float p   = (L >= 0.0f) ? r : e * r;  // sigmoid(L)

            a_wbce += weit * bce;
            a_int  += p * t * weit;
            a_tot  += (p + t) * weit;
        }
        // hazard note: next batch's wtot writes / Pbuf writes are ordered
        // against this batch's reads by the two __syncthreads above.
    }

    // ---- block reduction: wave shuffle + LDS + plain per-block stores ----
#pragma unroll
    for (int off = 32; off > 0; off >>= 1) {
        a_wbce += __shfl_down(a_wbce, off, 64);
        a_int  += __shfl_down(a_int,  off, 64);
        a_tot  += __shfl_down(a_tot,  off, 64);
    }

    __shared__ float red[3][8];
    if (lane == 0) {
        red[0][wave] = a_wbce; red[1][wave] = a_int; red[2][wave] = a_tot;
    }
    __syncthreads();
    if (threadIdx.x == 0) {
        float w = 0.0f, i2 = 0.0f, t2 = 0.0f;
#pragma unroll
        for (int k = 0; k < 8; ++k) { w += red[0][k]; i2 += red[1][k]; t2 += red[2][k]; }
        pbuf[blockIdx.x]            = w;
        pbuf[NBLK + blockIdx.x]     = i2;
        pbuf[2 * NBLK + blockIdx.x] = t2;
    }
}

// ---------------------------------------------------------------------------
// Finalize: reduce 1024 partials per quantity (double accum) + scalar.
// ---------------------------------------------------------------------------
__global__ __launch_bounds__(256) void finalize_kernel(const float* __restrict__ pbuf,
                                                       float* __restrict__ out) {
    const int tidx = threadIdx.x;
    double w = 0.0, i2 = 0.0, t2 = 0.0;
    for (int k = tidx; k < NBLK; k += 256) {
        w  += (double)pbuf[k];
        i2 += (double)pbuf[NBLK + k];
        t2 += (double)pbuf[2 * NBLK + k];
    }
#pragma unroll
    for (int off = 32; off > 0; off >>= 1) {
        w  += __shfl_down(w,  off, 64);
        i2 += __shfl_down(i2, off, 64);
        t2 += __shfl_down(t2, off, 64);
    }
    __shared__ double red[3][4];
    const int wave = tidx >> 6;
    if ((tidx & 63) == 0) { red[0][wave] = w; red[1][wave] = i2; red[2][wave] = t2; }
    __syncthreads();
    if (tidx == 0) {
        double ws = 0.0, is = 0.0, ts = 0.0;
        for (int k = 0; k < 4; ++k) { ws += red[0][k]; is += red[1][k]; ts += red[2][k]; }
        const double wbce   = ws / (double)NTOT;
        const double union_ = ts - is;
        const double wiou   = 1.0 - (is + 1.0) / (union_ + 1.0);
        out[0] = (float)(wbce + wiou);
    }
}

extern "C" void kernel_launch(void* const* d_in, const int* in_sizes, int n_in,
                              void* d_out, int out_size, void* d_ws, size_t ws_size,
                              hipStream_t stream) {
    const float* logits = (const float*)d_in[0];
    const float* targ   = (const float*)d_in[1];
    float* out          = (float*)d_out;
    float* pbuf         = (float*)d_ws;     // 3*NBLK floats (12 KB)

    mega_kernel<<<NBLK, 512, 0, stream>>>(logits, targ, pbuf);
    finalize_kernel<<<1, 256, 0, stream>>>(pbuf, out);
}

// Round 6
// 149.279 us; speedup vs baseline: 1.1701x; 1.1701x over previous
//
#include <hip/hip_runtime.h>
#include <math.h>

#define BATCH 64
#define HH 512
#define WW 512
#define KRAD 15
#define KSZ 31
#define NTOT ((size_t)BATCH * HH * WW)
#define TILE_Y 32
#define NCHUNK (HH / TILE_Y)            // 16
#define NBLK (BATCH * NCHUNK)           // 1024 blocks
#define HROWS (TILE_Y + 2 * KRAD)       // 62 LDS rows
#define HALF_Y (TILE_Y / 2)             // 16 rows per column-half thread

typedef _Float16 h8 __attribute__((ext_vector_type(8)));

// ---------------------------------------------------------------------------
// R4 structure (H-first: wave shuffle-scan -> fp16 LDS strip; V running sum)
// with 1024-thread blocks: 16 waves x 2 blocks/CU = 32 waves (100% ceiling)
// at the same 62 KB LDS strip. Stage 2 splits each column across 2 threads.
// ---------------------------------------------------------------------------
__global__ __launch_bounds__(1024, 8) void mega_kernel(const float* __restrict__ logits,
                                                       const float* __restrict__ targ,
                                                       float* __restrict__ pbuf) {
    __shared__ _Float16 Hlds[HROWS * WW];   // 62 KB

    const int b     = blockIdx.x >> 4;          // batch
    const int chunk = blockIdx.x & (NCHUNK - 1);
    const int y0    = chunk * TILE_Y;

    const int wave = threadIdx.x >> 6;          // 0..15
    const int lane = threadIdx.x & 63;

    // ---- Stage 1: H rows [y0-15, y0+46] -> LDS (fp16), 4 rows per wave ----
#pragma unroll
    for (int i = 0; i < 4; ++i) {
        const int r = i * 16 + wave;            // 0..63
        if (r >= HROWS) continue;               // wave-uniform
        const int y_abs = y0 - KRAD + r;

        h8 hv = {};
        if (y_abs >= 0 && y_abs < HH) {
            const float4* rp = (const float4*)(targ + ((size_t)b * HH + y_abs) * WW);
            float4 a  = rp[2 * lane];
            float4 b4 = rp[2 * lane + 1];
            float v[8] = {a.x, a.y, a.z, a.w, b4.x, b4.y, b4.z, b4.w};

            float T = 0.0f;
            float P[8];
#pragma unroll
            for (int j = 0; j < 8; ++j) { T += v[j]; P[j] = T; }

            float incl = T;
#pragma unroll
            for (int d = 1; d < 64; d <<= 1) {
                float n = __shfl_up(incl, d, 64);
                if (lane >= d) incl += n;
            }
            const float excl = incl - T;
            const float tot  = __shfl(incl, 63, 64);
#pragma unroll
            for (int j = 0; j < 8; ++j) P[j] += excl;

#pragma unroll
            for (int j = 0; j < 8; ++j) {
                const int q   = j + 15;             // 15..22 (compile-time)
                const int seg = lane + (q >> 3);
                float hi_sh = __shfl(P[q & 7], seg > 63 ? 63 : seg, 64);
                float hi    = (seg > 63) ? tot : hi_sh;
                float lo_sh = __shfl(P[j], lane >= 2 ? lane - 2 : 0, 64);
                float lo    = (lane >= 2) ? lo_sh : 0.0f;
                hv[j] = (_Float16)(hi - lo);
            }
        }
        *(h8*)&Hlds[r * WW + lane * 8] = hv;    // 16B aligned, contiguous
    }
    __syncthreads();

    // ---- Stage 2: 2 threads per column, 16 rows each ----
    const int x    = threadIdx.x & (WW - 1);    // column
    const int half = threadIdx.x >> 9;          // 0 or 1
    const int l0   = half * HALF_Y;             // local starting row

    const size_t base = ((size_t)b * HH + y0 + l0) * WW + x;
    const float* Tp = targ   + base;
    const float* Lp = logits + base;

    float vsum = 0.0f;
#pragma unroll
    for (int r = 0; r < KSZ; ++r) vsum += (float)Hlds[(l0 + r) * WW + x];

    const float inv_ksq = 1.0f / (float)(KSZ * KSZ);
    float a_wbce = 0.0f, a_int = 0.0f, a_tot = 0.0f;

#pragma unroll 4
    for (int j = 0; j < HALF_Y; ++j) {
        const float s = vsum * inv_ksq;
        const float t = Tp[(size_t)j * WW];
        const float L = __builtin_nontemporal_load(Lp + (size_t)j * WW);

        const float weit = 1.0f + 5.0f * fabsf(s - t);
        const float e  = __expf(-fabsf(L));
        const float r  = __builtin_amdgcn_rcpf(1.0f + e);
        const float lg = __logf(1.0f + e);          // softplus(-|L|)
        const float sp  = fmaxf(L, 0.0f) + lg;      // softplus(L)
        const float bce = sp - t * L;
        const float p   = (L >= 0.0f) ? r : e * r;  // sigmoid(L)

        a_wbce += weit * bce;
        a_int  += p * t * weit;
        a_tot  += (p + t) * weit;

        if (j < HALF_Y - 1) {
            const int l = l0 + j;
            vsum += (float)Hlds[(l + KSZ) * WW + x] - (float)Hlds[l * WW + x];
        }
    }

    // ---- Block reduction: wave shuffle + LDS + plain per-block stores ----
#pragma unroll
    for (int off = 32; off > 0; off >>= 1) {
        a_wbce += __shfl_down(a_wbce, off, 64);
        a_int  += __shfl_down(a_int,  off, 64);
        a_tot  += __shfl_down(a_tot,  off, 64);
    }

    __shared__ float red[3][16];
    if (lane == 0) {
        red[0][wave] = a_wbce; red[1][wave] = a_int; red[2][wave] = a_tot;
    }
    __syncthreads();
    if (threadIdx.x == 0) {
        float w = 0.0f, i2 = 0.0f, t2 = 0.0f;
#pragma unroll
        for (int k = 0; k < 16; ++k) { w += red[0][k]; i2 += red[1][k]; t2 += red[2][k]; }
        pbuf[blockIdx.x]            = w;
        pbuf[NBLK + blockIdx.x]     = i2;
        pbuf[2 * NBLK + blockIdx.x] = t2;
    }
}

// ---------------------------------------------------------------------------
// Finalize: reduce 1024 partials per quantity (double accum) + scalar.
// ---------------------------------------------------------------------------
__global__ __launch_bounds__(256) void finalize_kernel(const float* __restrict__ pbuf,
                                                       float* __restrict__ out) {
    const int tidx = threadIdx.x;
    double w = 0.0, i2 = 0.0, t2 = 0.0;
    for (int k = tidx; k < NBLK; k += 256) {
        w  += (double)pbuf[k];
        i2 += (double)pbuf[NBLK + k];
        t2 += (double)pbuf[2 * NBLK + k];
    }
#pragma unroll
    for (int off = 32; off > 0; off >>= 1) {
        w  += __shfl_down(w,  off, 64);
        i2 += __shfl_down(i2, off, 64);
        t2 += __shfl_down(t2, off, 64);
    }
    __shared__ double red[3][4];
    const int wave = tidx >> 6;
    if ((tidx & 63) == 0) { red[0][wave] = w; red[1][wave] = i2; red[2][wave] = t2; }
    __syncthreads();
    if (tidx == 0) {
        double ws = 0.0, is = 0.0, ts = 0.0;
        for (int k = 0; k < 4; ++k) { ws += red[0][k]; is += red[1][k]; ts += red[2][k]; }
        const double wbce   = ws / (double)NTOT;
        const double union_ = ts - is;
        const double wiou   = 1.0 - (is + 1.0) / (union_ + 1.0);
        out[0] = (float)(wbce + wiou);
    }
}

extern "C" void kernel_launch(void* const* d_in, const int* in_sizes, int n_in,
                              void* d_out, int out_size, void* d_ws, size_t ws_size,
                              hipStream_t stream) {
    const float* logits = (const float*)d_in[0];
    const float* targ   = (const float*)d_in[1];
    float* out          = (float*)d_out;
    float* pbuf         = (float*)d_ws;     // 3*NBLK floats (12 KB)

    mega_kernel<<<NBLK, 1024, 0, stream>>>(logits, targ, pbuf);
    finalize_kernel<<<1, 256, 0, stream>>>(pbuf, out);
}